// Round 7
// baseline (87.126 us; speedup 1.0000x reference)
//
#include <hip/hip_runtime.h>
#include <math.h>

#define NQ 14
#define DEPTH 6
#define BLOCK 512
#define TS 544u   // bytes per 16x16 f16 tile: 512 data + 32 pad (34 dwords % 32 = rotation 8)

typedef _Float16 h16;
typedef h16 h8 __attribute__((ext_vector_type(8)));
typedef float f4 __attribute__((ext_vector_type(4)));

template<int N> struct IC { static constexpr int value = N; };

// One block = one real component (comp = blockIdx&1) of one batch item (b = blockIdx>>1).
// Gates are real (RY + CZ diag) so re/im evolve independently; probs = re^2 + im^2
// recombined via atomicAdd on pre-zeroed d_out.
//
// Bit p = 13 - qubit. Groups: g0=[0-3] g1=[4-7] g2=[8-11] g3=[12,13,6,7] (identity
// on 6,7). Pass P applies g_P's 16x16 via mfma_f32_16x16x32_f16 (K upper half 0).
// View P layout: addr = T*TS + R*32 + G*2; G = g_P value (k-axis), R = g_{P+1}
// value (preserved row; becomes next G), T = 6-bit enum of the rest:
//   E0=[12,13,8,9,10,11] E1=[0,1,2,3,12,13] E2=[4,5,0,1,2,3] E3=[8,9,4,5,10,11]
// (enums chosen so every write's T'-low-2-bits = m -> bank-minimal with TS=544).
// After pass: lane(kg,m) holds D[R=kg*4+j][newG=m] for tile T=w*8+jt.
// CZ(d-1): intra pairs baked into layer-d B matrices; cross pairs (3,4),(7,8),
// (11,12) = bv sign flip at passes 0,1,2 when (lane&1)&&kg==1. Layer-5 CZ skipped.
__global__ __launch_bounds__(BLOCK, 6) void qsim_kernel(
    const float* __restrict__ x, const float* __restrict__ theta,
    const float* __restrict__ head_w, const float* __restrict__ head_b,
    float* __restrict__ out)   // (512,2) pre-zeroed, accumulated atomically
{
  extern __shared__ __align__(16) char sbuf[];   // 64 * 544 = 34816 B state
  __shared__ __align__(16) h16 Bm[24][256];      // B[n*16+k] per (d,p)
  __shared__ float2 gtab[DEPTH * NQ];            // (cos,sin) theta/2 at [d*14+bit]
  __shared__ float wT[2][64];                    // head wts over T bits {8,9,4,5,10,11}
  __shared__ float wR[2][16];                    // over bits {0,1,2,3}
  __shared__ float wM[2][16];                    // over bits {12,13,6,7}
  __shared__ float xc[NQ], xs[NQ];
  __shared__ float redbuf[16];

  const int t = threadIdx.x;
  const int b = blockIdx.x >> 1;
  const int comp = blockIdx.x & 1;
  const int lane = t & 63;
  const int w = t >> 6;        // 8 waves
  const int m = lane & 15;
  const int kg = lane >> 4;

  // ---- phase 0: small tables ----
  if (t < DEPTH * NQ) {
    int d = t / NQ, bit = t - d * NQ;
    float hg = 0.5f * theta[d * NQ + (13 - bit)];
    gtab[t] = make_float2(cosf(hg), sinf(hg));
  } else if (t >= 128 && t < 256) {
    int idx = t - 128, o = idx >> 6, v = idx & 63;
    const int pos[6] = {8, 9, 4, 5, 10, 11};
    float s = 0.f;
    #pragma unroll
    for (int i = 0; i < 6; ++i)
      s += ((v >> i) & 1) ? -head_w[o * NQ + pos[i]] : head_w[o * NQ + pos[i]];
    wT[o][v] = s;
  } else if (t >= 256 && t < 288) {
    int idx = t - 256, o = idx >> 4, v = idx & 15;
    float s = 0.f;
    #pragma unroll
    for (int i = 0; i < 4; ++i)
      s += ((v >> i) & 1) ? -head_w[o * NQ + i] : head_w[o * NQ + i];
    wR[o][v] = s;
  } else if (t >= 288 && t < 320) {
    int idx = t - 288, o = idx >> 4, v = idx & 15;
    const int pos[4] = {12, 13, 6, 7};
    float s = 0.f;
    #pragma unroll
    for (int i = 0; i < 4; ++i)
      s += ((v >> i) & 1) ? -head_w[o * NQ + pos[i]] : head_w[o * NQ + pos[i]];
    wM[o][v] = s;
  } else if (t >= 320 && t < 320 + NQ) {
    int bit = t - 320;
    float h = 0.5f * x[b * NQ + (13 - bit)];
    xc[bit] = cosf(h); xs[bit] = sinf(h);
  }
  __syncthreads();

  // ---- phase 1a: B matrices (arithmetic identical to rounds 5/6) ----
  #pragma unroll
  for (int i = 0; i < 12; ++i) {
    int e = t + (i << 9);                 // 512 threads x 12 = 6144 entries
    int pid = e >> 8, n = (e >> 4) & 15, k = e & 15;
    int d = pid >> 2, p = pid & 3;
    float val;
    if (p < 3) {
      val = 1.f;
      #pragma unroll
      for (int j = 0; j < 4; ++j) {
        float2 g = gtab[d * NQ + 4 * p + j];
        val *= ((n >> j) & 1) ? (((k >> j) & 1) ? g.x : g.y)
                              : (((k >> j) & 1) ? -g.y : g.x);
      }
      if (d >= 1) {   // intra-CZ pairs (4p,4p+1),(4p+1,4p+2),(4p+2,4p+3)
        int s = ((k & (k >> 1)) ^ ((k >> 1) & (k >> 2)) ^ ((k >> 2) & (k >> 3))) & 1;
        if (s) val = -val;
      }
    } else {          // g3 = [12,13,6,7]: G12 x G13 x I x I
      if ((((n ^ k) >> 2) & 3) != 0) val = 0.f;
      else {
        float2 gA = gtab[d * NQ + 12], gB = gtab[d * NQ + 13];
        float f0 = (n & 1) ? ((k & 1) ? gA.x : gA.y) : ((k & 1) ? -gA.y : gA.x);
        float f1 = ((n >> 1) & 1) ? (((k >> 1) & 1) ? gB.x : gB.y)
                                  : (((k >> 1) & 1) ? -gB.y : gB.x);
        val = f0 * f1;
        if (d >= 1 && (k & (k >> 1) & 1)) val = -val;   // intra pair (12,13)
      }
    }
    Bm[pid][n * 16 + k] = (h16)val;
  }

  // ---- phase 1b: initial product state -> view 0 (E0=[12,13,8,9,10,11]) ----
  #pragma unroll
  for (int rr = 0; rr < 2; ++rr) {
    int row = t * 2 + rr;                // 1024 rows of 32B
    int T = row >> 4, R = row & 15;
    // bits: b4..b7 = R; b12=T0,b13=T1,b8=T2,b9=T3,b10=T4,b11=T5
    float mhi = 1.f; int pc = 0;
    #pragma unroll
    for (int p = 4; p < 8; ++p) {
      int bit = (R >> (p - 4)) & 1;
      mhi *= bit ? xs[p] : xc[p]; pc += bit;
    }
    {
      const int bpos[6] = {12, 13, 8, 9, 10, 11};
      #pragma unroll
      for (int i = 0; i < 6; ++i) {
        int bit = (T >> i) & 1;
        mhi *= bit ? xs[bpos[i]] : xc[bpos[i]]; pc += bit;
      }
    }
    uint32_t base = (uint32_t)T * TS + (uint32_t)R * 32;
    #pragma unroll
    for (int half = 0; half < 2; ++half) {
      union { h16 h[8]; uint4 u; } pk;
      #pragma unroll
      for (int i2 = 0; i2 < 8; ++i2) {
        int i = half * 8 + i2;
        float mm = mhi;
        #pragma unroll
        for (int p = 0; p < 4; ++p)
          if ((i >> p) & 1) mm *= xs[p]; else mm = mm * xc[p];
        int e = (pc + __popc(i)) & 3;    // (-i)^e
        float v = (comp == 0) ? ((e == 0) ? mm : ((e == 2) ? -mm : 0.f))
                              : ((e == 1) ? -mm : ((e == 3) ? mm : 0.f));
        pk.h[i2] = (h16)v;
      }
      *(uint4*)(sbuf + base + half * 16) = pk.u;
    }
  }
  __syncthreads();

  const uint32_t rbase = (uint32_t)w * (8 * TS) + (uint32_t)m * 32 + (uint32_t)kg * 16;
  float l0 = 0.f, l1 = 0.f;

  auto pass = [&](auto pcst, int d, bool last) {
    constexpr int P = decltype(pcst)::value;
    h8 bv = {};
    if (kg < 2) bv = *(const h8*)(&Bm[d * 4 + P][m * 16 + kg * 8]);
    if (d >= 1 && P < 3 && (lane & 1) && kg == 1) {   // cross CZ pair sign
      union { h8 v; uint4 u; } f; f.v = bv;
      f.u.x ^= 0x80008000u; f.u.y ^= 0x80008000u;
      f.u.z ^= 0x80008000u; f.u.w ^= 0x80008000u;
      bv = f.v;
    }
    // write base into view P+1 (jt-terms added per iteration, constant-folded)
    uint32_t wbase;
    if constexpr (P == 0) {
      wbase = (uint32_t)m * TS + (uint32_t)w * 64 + (uint32_t)kg * 8;
    } else if constexpr (P == 1) {
      wbase = ((uint32_t)(m & 3) + 32u * (w & 1)) * TS
            + ((uint32_t)(w >> 1) + 4u * (m >> 2)) * 32 + (uint32_t)kg * 8;
    } else if constexpr (P == 2) {
      wbase = ((uint32_t)(m & 3) + 16u * (m >> 2)) * TS
            + (uint32_t)w * 64 + (uint32_t)kg * 8;
    } else {
      wbase = ((uint32_t)(m & 3) + 16u * (w >> 1)) * TS
            + ((uint32_t)(w & 1) * 2 + 4u * (m >> 2)) * 32 + (uint32_t)kg * 8;
    }
    float wadd0[4], wadd1[4];
    if (last) {
      #pragma unroll
      for (int j = 0; j < 4; ++j) {
        wadd0[j] = wR[0][4 * kg + j] + wM[0][m];
        wadd1[j] = wR[1][4 * kg + j] + wM[1][m];
      }
    }
    uint2 pk[8];
    #pragma unroll
    for (int jt = 0; jt < 8; ++jt) {
      h8 av = {};
      if (kg < 2) av = *(const h8*)(sbuf + rbase + (uint32_t)jt * TS);
      f4 acc = {0.f, 0.f, 0.f, 0.f};
      acc = __builtin_amdgcn_mfma_f32_16x16x32_f16(av, bv, acc, 0, 0, 0);
      if (!last) {
        union { h16 h[4]; uint2 u; } c2;
        c2.h[0] = (h16)acc[0]; c2.h[1] = (h16)acc[1];
        c2.h[2] = (h16)acc[2]; c2.h[3] = (h16)acc[3];
        pk[jt] = c2.u;
      } else {
        float wt0 = wT[0][w * 8 + jt], wt1 = wT[1][w * 8 + jt];
        #pragma unroll
        for (int j = 0; j < 4; ++j) {
          float pr = acc[j] * acc[j];
          l0 += pr * (wt0 + wadd0[j]);
          l1 += pr * (wt1 + wadd1[j]);
        }
      }
    }
    if (!last) {
      __syncthreads();   // all reads of this view done before overwrite
      #pragma unroll
      for (int jt = 0; jt < 8; ++jt) {
        uint32_t wa;
        if constexpr (P == 0)      wa = wbase + (uint32_t)(jt & 3) * (16 * TS) + (uint32_t)(jt >> 2) * 32;
        else if constexpr (P == 1) wa = wbase + (uint32_t)jt * (4 * TS);
        else if constexpr (P == 2) wa = wbase + (uint32_t)(jt & 3) * (4 * TS) + (uint32_t)(jt >> 2) * 32;
        else                       wa = wbase + (uint32_t)(jt & 3) * (4 * TS) + (uint32_t)(jt >> 2) * 32;
        *(uint2*)(sbuf + wa) = pk[jt];
      }
      __syncthreads();   // writes visible before next pass reads
    }
  };

  #pragma unroll 1
  for (int d = 0; d < DEPTH; ++d) {
    pass(IC<0>{}, d, false);
    pass(IC<1>{}, d, false);
    pass(IC<2>{}, d, false);
    pass(IC<3>{}, d, d == DEPTH - 1);
  }

  // ---- reduce partial logits and accumulate ----
  #pragma unroll
  for (int off = 32; off > 0; off >>= 1) {
    l0 += __shfl_xor(l0, off);
    l1 += __shfl_xor(l1, off);
  }
  if (lane == 0) { redbuf[w] = l0; redbuf[8 + w] = l1; }
  __syncthreads();
  if (t == 0) {
    float s0 = 0.f, s1 = 0.f;
    #pragma unroll
    for (int i = 0; i < 8; ++i) { s0 += redbuf[i]; s1 += redbuf[8 + i]; }
    if (comp == 0) { s0 += head_b[0]; s1 += head_b[1]; }
    atomicAdd(&out[b * 2 + 0], s0);
    atomicAdd(&out[b * 2 + 1], s1);
  }
}

extern "C" void kernel_launch(void* const* d_in, const int* in_sizes, int n_in,
                              void* d_out, int out_size, void* d_ws, size_t ws_size,
                              hipStream_t stream) {
    const float* x      = (const float*)d_in[0];
    const float* theta  = (const float*)d_in[1];
    const float* head_w = (const float*)d_in[2];
    const float* head_b = (const float*)d_in[3];
    float* outp = (float*)d_out;
    const int batch = in_sizes[0] / NQ;  // 512
    hipMemsetAsync(outp, 0, (size_t)out_size * sizeof(float), stream);
    qsim_kernel<<<batch * 2, BLOCK, 64 * TS, stream>>>(x, theta, head_w, head_b, outp);
}

// Round 9
// 71.796 us; speedup vs baseline: 1.2135x; 1.2135x over previous
//
#include <hip/hip_runtime.h>
#include <math.h>

#define NQ 14
#define DEPTH 6
#define BLOCK 512
#define TS 528u   // bytes per 16x16 f16 tile: 512 data + 16 pad (132 dwords = 4 mod 32)

typedef _Float16 h16;
typedef h16 h8 __attribute__((ext_vector_type(8)));
typedef float f4 __attribute__((ext_vector_type(4)));

// One block = one real component (comp=blockIdx&1) of item b=blockIdx>>1 (gates real).
// Bit p = 13 - qubit. Groups g0=[0-3] g1=[4-7] g2=[8-11] g3grp=[12,13,6,7] (I on 6,7).
// PAIRED passes per half-layer: one LDS read -> MFMA(state,G) -> in-wave bpermute
// fan-in -> MFMA(G',state) -> one LDS write. View X tiles (rows g1 x cols g0),
// T=bits[8..13]; view Y tiles (rows g3grp x cols g2), Ty=[g0(4),b4,b5].
// addr = T*TS + row*32 + col*2. Wave tile maps: half A T=w*8+jt; half B
// Ty=(w&1)*8+jt+16*(w>>1) -> writes are jt-contiguous b128 after in-reg regroup.
// CZ(d-1): intra pairs + cross pairs (n&1)&&(k&8) baked into Bm (same composite
// operator as validated rounds 5-7). Layer-5 CZ skipped (probs sign-invariant).
// ROUND-9 FIX: state A-fragment loads guarded with kg<2 (kg>=2 lanes read the
// uninitialized tile pad in round 8 -> NaN via MFMA's NaN*0). Pads also zeroed.
__global__ __launch_bounds__(BLOCK, 6) void qsim_kernel(
    const float* __restrict__ x, const float* __restrict__ theta,
    const float* __restrict__ head_w, const float* __restrict__ head_b,
    float* __restrict__ out)   // (512,2) pre-zeroed, accumulated atomically
{
  extern __shared__ __align__(16) char sbuf[];   // 33856 B (64*528 + pad)
  __shared__ __align__(16) h16 Bm[24][256];      // M[n*16+k] per (d,p), signs baked
  __shared__ float2 gtab[DEPTH * NQ];
  __shared__ float wA[2][16], wB[2][16], wC[2][4], wD[2][4], wE[2][4];
  __shared__ float xc[NQ], xs[NQ];
  __shared__ float redbuf[16];

  const int t = threadIdx.x;
  const int b = blockIdx.x >> 1;
  const int comp = blockIdx.x & 1;
  const int lane = t & 63;
  const int w = t >> 6;        // 8 waves
  const int m = lane & 15;
  const int kg = lane >> 4;

  // ---- phase 0: small tables ----
  if (t < DEPTH * NQ) {
    int d = t / NQ, bit = t - d * NQ;
    float hg = 0.5f * theta[d * NQ + (13 - bit)];
    gtab[t] = make_float2(cosf(hg), sinf(hg));
  } else if (t >= 128 && t < 160) {        // wA: bits 0-3
    int o = (t - 128) >> 4, v = t & 15; float s = 0.f;
    #pragma unroll
    for (int i = 0; i < 4; ++i) s += ((v >> i) & 1) ? -head_w[o*NQ+i] : head_w[o*NQ+i];
    wA[o][v] = s;
  } else if (t >= 160 && t < 192) {        // wB: bits 8-11
    int o = (t - 160) >> 4, v = t & 15; float s = 0.f;
    #pragma unroll
    for (int i = 0; i < 4; ++i) s += ((v >> i) & 1) ? -head_w[o*NQ+8+i] : head_w[o*NQ+8+i];
    wB[o][v] = s;
  } else if (t >= 192 && t < 200) {        // wC: bits 4,5
    int o = (t - 192) >> 2, v = t & 3;
    float s = ((v & 1) ? -head_w[o*NQ+4] : head_w[o*NQ+4])
            + ((v & 2) ? -head_w[o*NQ+5] : head_w[o*NQ+5]);
    wC[o][v] = s;
  } else if (t >= 200 && t < 208) {        // wD: bits 6,7
    int o = (t - 200) >> 2, v = t & 3;
    float s = ((v & 1) ? -head_w[o*NQ+6] : head_w[o*NQ+6])
            + ((v & 2) ? -head_w[o*NQ+7] : head_w[o*NQ+7]);
    wD[o][v] = s;
  } else if (t >= 208 && t < 216) {        // wE: bits 12,13
    int o = (t - 208) >> 2, v = t & 3;
    float s = ((v & 1) ? -head_w[o*NQ+12] : head_w[o*NQ+12])
            + ((v & 2) ? -head_w[o*NQ+13] : head_w[o*NQ+13]);
    wE[o][v] = s;
  } else if (t >= 224 && t < 224 + NQ) {
    int bit = t - 224;
    float h = 0.5f * x[b * NQ + (13 - bit)];
    xc[bit] = cosf(h); xs[bit] = sinf(h);
  }
  if (t >= 256 && t < 320)                 // zero the 16B pad of each tile
    *(uint4*)(sbuf + (uint32_t)(t - 256) * TS + 512) = make_uint4(0, 0, 0, 0);
  __syncthreads();

  // ---- phase 1a: Bm (rounds 5-7 arithmetic; all CZ signs baked) ----
  #pragma unroll
  for (int i = 0; i < 12; ++i) {
    int e = t + (i << 9);
    int pid = e >> 8, n = (e >> 4) & 15, k = e & 15;
    int d = pid >> 2, p = pid & 3;
    float val;
    if (p < 3) {
      val = 1.f;
      #pragma unroll
      for (int j = 0; j < 4; ++j) {
        float2 g = gtab[d * NQ + 4 * p + j];
        val *= ((n >> j) & 1) ? (((k >> j) & 1) ? g.x : g.y)
                              : (((k >> j) & 1) ? -g.y : g.x);
      }
      if (d >= 1) {
        int s = ((k & (k >> 1)) ^ ((k >> 1) & (k >> 2)) ^ ((k >> 2) & (k >> 3))) & 1;
        if (s) val = -val;
        if ((n & 1) && (k & 8)) val = -val;    // cross-pair sign (as rounds 5-7)
      }
    } else {          // g3grp = [12,13,6,7]: G12 x G13 x I x I
      if ((((n ^ k) >> 2) & 3) != 0) val = 0.f;
      else {
        float2 gA = gtab[d * NQ + 12], gB = gtab[d * NQ + 13];
        float f0 = (n & 1) ? ((k & 1) ? gA.x : gA.y) : ((k & 1) ? -gA.y : gA.x);
        float f1 = ((n >> 1) & 1) ? (((k >> 1) & 1) ? gB.x : gB.y)
                                  : (((k >> 1) & 1) ? -gB.y : gB.x);
        val = f0 * f1;
        if (d >= 1 && (k & (k >> 1) & 1)) val = -val;
      }
    }
    Bm[pid][n * 16 + k] = (h16)val;
  }

  // ---- phase 1b: init product state -> view X ----
  {
    float Mt = 1.f;
    #pragma unroll
    for (int p = 5; p < 14; ++p) Mt *= ((t >> (p - 5)) & 1) ? xs[p] : xc[p];
    const int pct = __popc((unsigned)t);
    uint32_t base = (uint32_t)(t >> 3) * TS + (uint32_t)((2 * t) & 15) * 32;
    #pragma unroll
    for (int g = 0; g < 4; ++g) {
      union { h16 h[8]; uint4 u; } pk;
      #pragma unroll
      for (int i = 0; i < 8; ++i) {
        int j = g * 8 + i;
        float mm = Mt;
        #pragma unroll
        for (int p = 0; p < 5; ++p) mm *= ((j >> p) & 1) ? xs[p] : xc[p];
        int e = (pct + __popc((unsigned)j)) & 3;   // (-i)^e
        float v = (comp == 0) ? ((e == 0) ? mm : ((e == 2) ? -mm : 0.f))
                              : ((e == 1) ? -mm : ((e == 3) ? mm : 0.f));
        pk.h[i] = (h16)v;
      }
      *(uint4*)(sbuf + base + (uint32_t)(g >> 1) * 32 + (uint32_t)(g & 1) * 16) = pk.u;
    }
  }
  __syncthreads();

  const uint32_t raA = (uint32_t)w * (8 * TS) + (uint32_t)m * 32 + (uint32_t)kg * 16;
  const uint32_t raB = (uint32_t)((w & 1) * 8 + 16 * (w >> 1)) * TS
                     + (uint32_t)m * 32 + (uint32_t)kg * 16;
  const uint32_t wbase = (uint32_t)m * TS + ((uint32_t)(w >> 1) + 4u * (uint32_t)kg) * 32
                       + (uint32_t)((w & 1) * 16);
  const int aA = (kg * 32 + m) * 4, aB2 = aA + 64;

  float l0 = 0.f, l1 = 0.f;

  // paired half-layer: MFMA(state,gB) -> bpermute fan-in -> MFMA(gA,state) -> write
  auto do_half = [&](uint32_t rbase, h8 gB, h8 gA, bool last) {
    h8 av[8];
    #pragma unroll
    for (int jt = 0; jt < 8; ++jt) {
      av[jt] = h8{};
      if (kg < 2)                      // ROUND-9 FIX: guard (kg>=2 = K zero pad)
        av[jt] = *(const h8*)(sbuf + rbase + (uint32_t)jt * TS);
    }
    uint32_t qk[8][2];
    float bs0 = 0.f, bs1 = 0.f, we0[4], we1[4];
    if (last) {
      bs0 = wB[0][m] + wC[0][w >> 1] + wD[0][kg];
      bs1 = wB[1][m] + wC[1][w >> 1] + wD[1][kg];
      #pragma unroll
      for (int j = 0; j < 4; ++j) { we0[j] = wE[0][j]; we1[j] = wE[1][j]; }
    }
    #pragma unroll
    for (int jt = 0; jt < 8; ++jt) {
      f4 acc = {0.f, 0.f, 0.f, 0.f};
      acc = __builtin_amdgcn_mfma_f32_16x16x32_f16(av[jt], gB, acc, 0, 0, 0);
      union { h16 h[4]; uint32_t d[2]; } c1;
      c1.h[0] = (h16)acc[0]; c1.h[1] = (h16)acc[1];
      c1.h[2] = (h16)acc[2]; c1.h[3] = (h16)acc[3];
      union { uint32_t d[4]; h8 h; } bq;
      bq.d[0] = (uint32_t)__builtin_amdgcn_ds_bpermute(aA,  (int)c1.d[0]);
      bq.d[1] = (uint32_t)__builtin_amdgcn_ds_bpermute(aA,  (int)c1.d[1]);
      bq.d[2] = (uint32_t)__builtin_amdgcn_ds_bpermute(aB2, (int)c1.d[0]);
      bq.d[3] = (uint32_t)__builtin_amdgcn_ds_bpermute(aB2, (int)c1.d[1]);
      f4 acc2 = {0.f, 0.f, 0.f, 0.f};
      acc2 = __builtin_amdgcn_mfma_f32_16x16x32_f16(gA, bq.h, acc2, 0, 0, 0);
      if (!last) {
        union { h16 h[4]; uint32_t d[2]; } c2;
        c2.h[0] = (h16)acc2[0]; c2.h[1] = (h16)acc2[1];
        c2.h[2] = (h16)acc2[2]; c2.h[3] = (h16)acc2[3];
        qk[jt][0] = c2.d[0]; qk[jt][1] = c2.d[1];
      } else {
        float wt0 = wA[0][(w & 1) * 8 + jt], wt1 = wA[1][(w & 1) * 8 + jt];
        #pragma unroll
        for (int j = 0; j < 4; ++j) {
          float pr = acc2[j] * acc2[j];
          l0 += pr * (bs0 + wt0 + we0[j]);
          l1 += pr * (bs1 + wt1 + we1[j]);
        }
      }
    }
    if (!last) {
      __syncthreads();   // all reads of this view done before overwrite
      #pragma unroll
      for (int r = 0; r < 4; ++r) {
        uint32_t o[4];
        #pragma unroll
        for (int q = 0; q < 4; ++q) {
          uint32_t lo = qk[2 * q][r >> 1], hi = qk[2 * q + 1][r >> 1];
          o[q] = (r & 1) ? ((lo >> 16) | (hi & 0xffff0000u))
                         : ((lo & 0xffffu) | (hi << 16));
        }
        *(uint4*)(sbuf + wbase + (uint32_t)r * (16 * TS)) =
            make_uint4(o[0], o[1], o[2], o[3]);
      }
      __syncthreads();   // writes visible before next half reads
    }
  };

  #pragma unroll 1
  for (int d = 0; d < DEPTH; ++d) {
    h8 g0f = {}, g1f = {}, g2f = {}, g3f = {};
    if (kg < 2) {
      const uint32_t fo = (uint32_t)(m * 16 + kg * 8) * 2;
      g0f = *(const h8*)((const char*)&Bm[d * 4 + 0][0] + fo);
      g1f = *(const h8*)((const char*)&Bm[d * 4 + 1][0] + fo);
      g2f = *(const h8*)((const char*)&Bm[d * 4 + 2][0] + fo);
      g3f = *(const h8*)((const char*)&Bm[d * 4 + 3][0] + fo);
    }
    do_half(raA, g0f, g1f, false);                 // passes 0,1 (g0 then g1)
    do_half(raB, g2f, g3f, d == DEPTH - 1);        // passes 2,3 (g2 then g3grp)
  }

  // ---- reduce partial logits, accumulate re/im via atomics ----
  #pragma unroll
  for (int off = 32; off > 0; off >>= 1) {
    l0 += __shfl_xor(l0, off);
    l1 += __shfl_xor(l1, off);
  }
  if (lane == 0) { redbuf[w] = l0; redbuf[8 + w] = l1; }
  __syncthreads();
  if (t == 0) {
    float s0 = 0.f, s1 = 0.f;
    #pragma unroll
    for (int i = 0; i < 8; ++i) { s0 += redbuf[i]; s1 += redbuf[8 + i]; }
    if (comp == 0) { s0 += head_b[0]; s1 += head_b[1]; }
    atomicAdd(&out[b * 2 + 0], s0);
    atomicAdd(&out[b * 2 + 1], s1);
  }
}

extern "C" void kernel_launch(void* const* d_in, const int* in_sizes, int n_in,
                              void* d_out, int out_size, void* d_ws, size_t ws_size,
                              hipStream_t stream) {
    const float* x      = (const float*)d_in[0];
    const float* theta  = (const float*)d_in[1];
    const float* head_w = (const float*)d_in[2];
    const float* head_b = (const float*)d_in[3];
    float* outp = (float*)d_out;
    const int batch = in_sizes[0] / NQ;  // 512
    hipMemsetAsync(outp, 0, (size_t)out_size * sizeof(float), stream);
    qsim_kernel<<<batch * 2, BLOCK, 33856, stream>>>(x, theta, head_w, head_b, outp);
}

// Round 10
// 61.901 us; speedup vs baseline: 1.4075x; 1.1599x over previous
//
#include <hip/hip_runtime.h>
#include <math.h>

#define NQ 14
#define DEPTH 6
#define BLOCK 512
#define TS 528u   // bytes per 16x16 f16 tile: 512 data + 16 pad (132 dwords = 4 mod 32)

typedef _Float16 h16;
typedef h16 h4 __attribute__((ext_vector_type(4)));
typedef float f4 __attribute__((ext_vector_type(4)));

// One block = one real component (comp=blockIdx&1) of item b=blockIdx>>1 (gates real).
// Bit p = 13 - qubit. Groups g0=[0-3] g1=[4-7] g2=[8-11] g3grp=[12,13,6,7] (I on 6,7).
// PAIRED passes per half-layer, both on mfma_f32_16x16x16f16:
//   MFMA1: A = state tile (rows=preserved axis, k=cols=g_P), B = G_P   -> D1
//   MFMA2: A = G_{P+1},  B = D1 REGISTERS VERBATIM (16x16x16 B-layout == D-layout)
// -> no cross-lane fan-in at all (round 9's 32 bpermutes/half deleted).
// View X tiles (rows g1 x cols g0), T=bits[8..13]; view Y tiles (rows g3grp x
// cols g2), Ty=[g0(4),b4,b5]. addr = T*TS + row*32 + col*2. Wave tile maps:
// half A T=w*8+jt; half B Ty=(w&1)*8+jt+16*(w>>1); writes are b128 after the
// in-register jt-pair regroup (D2 lane layout identical to round 9 -> same maps).
// CZ(d-1): intra pairs + cross pairs (n&1)&&(k&8) baked into Bm. Layer-5 CZ
// skipped (probs sign-invariant).
__global__ __launch_bounds__(BLOCK, 6) void qsim_kernel(
    const float* __restrict__ x, const float* __restrict__ theta,
    const float* __restrict__ head_w, const float* __restrict__ head_b,
    float* __restrict__ out)   // (512,2) pre-zeroed, accumulated atomically
{
  extern __shared__ __align__(16) char sbuf[];   // 33856 B (64*528 + slack)
  __shared__ __align__(16) h16 Bm[24][256];      // M[n*16+k] per (d,p), signs baked
  __shared__ float2 gtab[DEPTH * NQ];
  __shared__ float wA[2][16], wB[2][16], wC[2][4], wD[2][4], wE[2][4];
  __shared__ float xc[NQ], xs[NQ];
  __shared__ float redbuf[16];

  const int t = threadIdx.x;
  const int b = blockIdx.x >> 1;
  const int comp = blockIdx.x & 1;
  const int lane = t & 63;
  const int w = t >> 6;        // 8 waves
  const int m = lane & 15;
  const int kg = lane >> 4;

  // ---- phase 0: small tables ----
  if (t < DEPTH * NQ) {
    int d = t / NQ, bit = t - d * NQ;
    float hg = 0.5f * theta[d * NQ + (13 - bit)];
    gtab[t] = make_float2(cosf(hg), sinf(hg));
  } else if (t >= 128 && t < 160) {        // wA: bits 0-3
    int o = (t - 128) >> 4, v = t & 15; float s = 0.f;
    #pragma unroll
    for (int i = 0; i < 4; ++i) s += ((v >> i) & 1) ? -head_w[o*NQ+i] : head_w[o*NQ+i];
    wA[o][v] = s;
  } else if (t >= 160 && t < 192) {        // wB: bits 8-11
    int o = (t - 160) >> 4, v = t & 15; float s = 0.f;
    #pragma unroll
    for (int i = 0; i < 4; ++i) s += ((v >> i) & 1) ? -head_w[o*NQ+8+i] : head_w[o*NQ+8+i];
    wB[o][v] = s;
  } else if (t >= 192 && t < 200) {        // wC: bits 4,5
    int o = (t - 192) >> 2, v = t & 3;
    float s = ((v & 1) ? -head_w[o*NQ+4] : head_w[o*NQ+4])
            + ((v & 2) ? -head_w[o*NQ+5] : head_w[o*NQ+5]);
    wC[o][v] = s;
  } else if (t >= 200 && t < 208) {        // wD: bits 6,7
    int o = (t - 200) >> 2, v = t & 3;
    float s = ((v & 1) ? -head_w[o*NQ+6] : head_w[o*NQ+6])
            + ((v & 2) ? -head_w[o*NQ+7] : head_w[o*NQ+7]);
    wD[o][v] = s;
  } else if (t >= 208 && t < 216) {        // wE: bits 12,13
    int o = (t - 208) >> 2, v = t & 3;
    float s = ((v & 1) ? -head_w[o*NQ+12] : head_w[o*NQ+12])
            + ((v & 2) ? -head_w[o*NQ+13] : head_w[o*NQ+13]);
    wE[o][v] = s;
  } else if (t >= 224 && t < 224 + NQ) {
    int bit = t - 224;
    float h = 0.5f * x[b * NQ + (13 - bit)];
    xc[bit] = cosf(h); xs[bit] = sinf(h);
  }
  __syncthreads();

  // ---- phase 1a: Bm (rounds 5-9 arithmetic; all CZ signs baked) ----
  #pragma unroll
  for (int i = 0; i < 12; ++i) {
    int e = t + (i << 9);
    int pid = e >> 8, n = (e >> 4) & 15, k = e & 15;
    int d = pid >> 2, p = pid & 3;
    float val;
    if (p < 3) {
      val = 1.f;
      #pragma unroll
      for (int j = 0; j < 4; ++j) {
        float2 g = gtab[d * NQ + 4 * p + j];
        val *= ((n >> j) & 1) ? (((k >> j) & 1) ? g.x : g.y)
                              : (((k >> j) & 1) ? -g.y : g.x);
      }
      if (d >= 1) {
        int s = ((k & (k >> 1)) ^ ((k >> 1) & (k >> 2)) ^ ((k >> 2) & (k >> 3))) & 1;
        if (s) val = -val;
        if ((n & 1) && (k & 8)) val = -val;    // cross-pair sign (as rounds 5-9)
      }
    } else {          // g3grp = [12,13,6,7]: G12 x G13 x I x I
      if ((((n ^ k) >> 2) & 3) != 0) val = 0.f;
      else {
        float2 gA = gtab[d * NQ + 12], gB = gtab[d * NQ + 13];
        float f0 = (n & 1) ? ((k & 1) ? gA.x : gA.y) : ((k & 1) ? -gA.y : gA.x);
        float f1 = ((n >> 1) & 1) ? (((k >> 1) & 1) ? gB.x : gB.y)
                                  : (((k >> 1) & 1) ? -gB.y : gB.x);
        val = f0 * f1;
        if (d >= 1 && (k & (k >> 1) & 1)) val = -val;
      }
    }
    Bm[pid][n * 16 + k] = (h16)val;
  }

  // ---- phase 1b: init product state -> view X ----
  {
    float Mt = 1.f;
    #pragma unroll
    for (int p = 5; p < 14; ++p) Mt *= ((t >> (p - 5)) & 1) ? xs[p] : xc[p];
    const int pct = __popc((unsigned)t);
    uint32_t base = (uint32_t)(t >> 3) * TS + (uint32_t)((2 * t) & 15) * 32;
    #pragma unroll
    for (int g = 0; g < 4; ++g) {
      union { h16 h[8]; uint4 u; } pk;
      #pragma unroll
      for (int i = 0; i < 8; ++i) {
        int j = g * 8 + i;
        float mm = Mt;
        #pragma unroll
        for (int p = 0; p < 5; ++p) mm *= ((j >> p) & 1) ? xs[p] : xc[p];
        int e = (pct + __popc((unsigned)j)) & 3;   // (-i)^e
        float v = (comp == 0) ? ((e == 0) ? mm : ((e == 2) ? -mm : 0.f))
                              : ((e == 1) ? -mm : ((e == 3) ? mm : 0.f));
        pk.h[i] = (h16)v;
      }
      *(uint4*)(sbuf + base + (uint32_t)(g >> 1) * 32 + (uint32_t)(g & 1) * 16) = pk.u;
    }
  }
  __syncthreads();

  // A-fragment (16x16x16): lane reads row m, cols kg*4..kg*4+3 -> b64, ALL lanes
  const uint32_t raA = (uint32_t)w * (8 * TS) + (uint32_t)m * 32 + (uint32_t)kg * 8;
  const uint32_t raB = (uint32_t)((w & 1) * 8 + 16 * (w >> 1)) * TS
                     + (uint32_t)m * 32 + (uint32_t)kg * 8;
  const uint32_t wbase = (uint32_t)m * TS + ((uint32_t)(w >> 1) + 4u * (uint32_t)kg) * 32
                       + (uint32_t)((w & 1) * 16);
  // gate fragment offset (both A- and B-side of x16): Bm[m*16 + kg*4 + i]
  const uint32_t gfo = (uint32_t)(m * 16 + kg * 4) * 2;

  float l0 = 0.f, l1 = 0.f;

  // paired half-layer: MFMA1(state, gB) -> MFMA2(gA, D1-as-B) -> write
  auto do_half = [&](uint32_t rbase, h4 gB, h4 gA, bool last) {
    h4 av[8];
    #pragma unroll
    for (int jt = 0; jt < 8; ++jt)
      av[jt] = *(const h4*)(sbuf + rbase + (uint32_t)jt * TS);
    uint32_t qk[8][2];
    float bs0 = 0.f, bs1 = 0.f, we0[4], we1[4];
    if (last) {
      bs0 = wB[0][m] + wC[0][w >> 1] + wD[0][kg];
      bs1 = wB[1][m] + wC[1][w >> 1] + wD[1][kg];
      #pragma unroll
      for (int j = 0; j < 4; ++j) { we0[j] = wE[0][j]; we1[j] = wE[1][j]; }
    }
    #pragma unroll
    for (int jt = 0; jt < 8; ++jt) {
      f4 acc = {0.f, 0.f, 0.f, 0.f};
      acc = __builtin_amdgcn_mfma_f32_16x16x16f16(av[jt], gB, acc, 0, 0, 0);
      union { h16 h[4]; h4 v; uint32_t d[2]; } c1;
      c1.h[0] = (h16)acc[0]; c1.h[1] = (h16)acc[1];
      c1.h[2] = (h16)acc[2]; c1.h[3] = (h16)acc[3];
      f4 acc2 = {0.f, 0.f, 0.f, 0.f};
      acc2 = __builtin_amdgcn_mfma_f32_16x16x16f16(gA, c1.v, acc2, 0, 0, 0);
      if (!last) {
        union { h16 h[4]; uint32_t d[2]; } c2;
        c2.h[0] = (h16)acc2[0]; c2.h[1] = (h16)acc2[1];
        c2.h[2] = (h16)acc2[2]; c2.h[3] = (h16)acc2[3];
        qk[jt][0] = c2.d[0]; qk[jt][1] = c2.d[1];
      } else {
        float wt0 = wA[0][(w & 1) * 8 + jt], wt1 = wA[1][(w & 1) * 8 + jt];
        #pragma unroll
        for (int j = 0; j < 4; ++j) {
          float pr = acc2[j] * acc2[j];
          l0 += pr * (bs0 + wt0 + we0[j]);
          l1 += pr * (bs1 + wt1 + we1[j]);
        }
      }
    }
    if (!last) {
      __syncthreads();   // all reads of this view done before overwrite
      #pragma unroll
      for (int r = 0; r < 4; ++r) {
        uint32_t o[4];
        #pragma unroll
        for (int q = 0; q < 4; ++q) {
          uint32_t lo = qk[2 * q][r >> 1], hi = qk[2 * q + 1][r >> 1];
          o[q] = (r & 1) ? ((lo >> 16) | (hi & 0xffff0000u))
                         : ((lo & 0xffffu) | (hi << 16));
        }
        *(uint4*)(sbuf + wbase + (uint32_t)r * (16 * TS)) =
            make_uint4(o[0], o[1], o[2], o[3]);
      }
      __syncthreads();   // writes visible before next half reads
    }
  };

  #pragma unroll 1
  for (int d = 0; d < DEPTH; ++d) {
    const char* base = (const char*)&Bm[d * 4 + 0][0];
    h4 g0f = *(const h4*)(base + gfo);
    h4 g1f = *(const h4*)(base + 512 + gfo);
    h4 g2f = *(const h4*)(base + 1024 + gfo);
    h4 g3f = *(const h4*)(base + 1536 + gfo);
    do_half(raA, g0f, g1f, false);                 // passes 0,1 (g0 then g1)
    do_half(raB, g2f, g3f, d == DEPTH - 1);        // passes 2,3 (g2 then g3grp)
  }

  // ---- reduce partial logits, accumulate re/im via atomics ----
  #pragma unroll
  for (int off = 32; off > 0; off >>= 1) {
    l0 += __shfl_xor(l0, off);
    l1 += __shfl_xor(l1, off);
  }
  if (lane == 0) { redbuf[w] = l0; redbuf[8 + w] = l1; }
  __syncthreads();
  if (t == 0) {
    float s0 = 0.f, s1 = 0.f;
    #pragma unroll
    for (int i = 0; i < 8; ++i) { s0 += redbuf[i]; s1 += redbuf[8 + i]; }
    if (comp == 0) { s0 += head_b[0]; s1 += head_b[1]; }
    atomicAdd(&out[b * 2 + 0], s0);
    atomicAdd(&out[b * 2 + 1], s1);
  }
}

extern "C" void kernel_launch(void* const* d_in, const int* in_sizes, int n_in,
                              void* d_out, int out_size, void* d_ws, size_t ws_size,
                              hipStream_t stream) {
    const float* x      = (const float*)d_in[0];
    const float* theta  = (const float*)d_in[1];
    const float* head_w = (const float*)d_in[2];
    const float* head_b = (const float*)d_in[3];
    float* outp = (float*)d_out;
    const int batch = in_sizes[0] / NQ;  // 512
    hipMemsetAsync(outp, 0, (size_t)out_size * sizeof(float), stream);
    qsim_kernel<<<batch * 2, BLOCK, 33856, stream>>>(x, theta, head_w, head_b, outp);
}